// Round 5
// baseline (497.459 us; speedup 1.0000x reference)
//
#include <hip/hip_runtime.h>

// MoE: T=8192, D_MODEL=1024, D_FF=1024, E=8, top-2.
// Router fp32; FFN bf16 MFMA (m97-style async staging + XOR swizzle).
// R5: mega-kernel = cvt3 + router + (last-block) scatter + finalize in ONE launch.

#define T_TOK   8192
#define DM      1024
#define DFF     1024
#define NE      8
#define CAP     16384
#define R1_BLK  (T_TOK / 4)    // 2048 router blocks
#define CVT_BLK 2048           // conversion blocks

typedef __attribute__((ext_vector_type(8))) short bf16x8;
typedef __attribute__((ext_vector_type(4))) float f32x4;

#define ASYNC16(gp, lp) __builtin_amdgcn_global_load_lds( \
    (const __attribute__((address_space(1))) unsigned int*)(gp), \
    (__attribute__((address_space(3))) unsigned int*)(lp), 16, 0, 0)

__device__ __forceinline__ unsigned short f2bf(float f) {
    union { float f; unsigned u; } c; c.f = f;
    unsigned r = c.u + 0x7fffu + ((c.u >> 16) & 1u);
    return (unsigned short)(r >> 16);
}
__device__ __forceinline__ float bf2f(unsigned short h) {
    union { unsigned u; float f; } c; c.u = ((unsigned)h) << 16;
    return c.f;
}

// ---------------- mega: cvt3 || router; last router block: scatter + finalize --------
__global__ __launch_bounds__(256) void mega_kernel(
    const float* __restrict__ x, const float* __restrict__ gate_w,
    const float* __restrict__ s0, const float* __restrict__ s1, const float* __restrict__ s2,
    unsigned short* __restrict__ d0, unsigned short* __restrict__ d1, unsigned short* __restrict__ d2,
    unsigned short* __restrict__ xb,
    int* __restrict__ topi, float2* __restrict__ topw, float* __restrict__ psum_part,
    int* __restrict__ elist, int* __restrict__ ecnt, int* __restrict__ rdone,
    float* __restrict__ out_tail)
{
    int tid = threadIdx.x;

    if (blockIdx.x >= R1_BLK) {
        // ---- cvt role: 3 weight tensors, 12 float4 per thread, grid-strided ----
        int base = (blockIdx.x - R1_BLK) * 256 + tid;
        #pragma unroll
        for (int it = 0; it < 12; ++it) {
            int idx = base + it * (CVT_BLK * 256);
            int seg = idx >> 21;                    // 2^21 float4 per tensor
            int off = (idx & ((1 << 21) - 1)) * 4;
            const float* s = (seg == 0) ? s0 : (seg == 1) ? s1 : s2;
            unsigned short* d = (seg == 0) ? d0 : (seg == 1) ? d1 : d2;
            float4 v = *(const float4*)(s + off);
            ushort4 o;
            o.x = f2bf(v.x); o.y = f2bf(v.y); o.z = f2bf(v.z); o.w = f2bf(v.w);
            *(ushort4*)(d + off) = o;
        }
        return;
    }

    // ---- router role ----
    __shared__ float gw[NE * DM];
    __shared__ float blk_psum[NE];
    __shared__ int lcnt[NE], rbase[NE], cb8[NE];
    __shared__ float parts[NE];
    __shared__ int lastflag;

    for (int i = tid; i < NE * DM; i += 256) gw[i] = gate_w[i];
    if (tid < NE) blk_psum[tid] = 0.f;
    __syncthreads();

    int wv = tid >> 6, lane = tid & 63;
    int t = blockIdx.x * 4 + wv;

    float acc[NE];
    #pragma unroll
    for (int e = 0; e < NE; ++e) acc[e] = 0.f;
    const float* xr = x + (size_t)t * DM;
    unsigned short* xbr = xb + (size_t)t * DM;
    #pragma unroll 4
    for (int i = 0; i < DM / 64; ++i) {
        float xv = xr[i * 64 + lane];
        xbr[i * 64 + lane] = f2bf(xv);
        #pragma unroll
        for (int e = 0; e < NE; ++e)
            acc[e] += xv * gw[e * DM + i * 64 + lane];
    }
    #pragma unroll
    for (int e = 0; e < NE; ++e) {
        float v = acc[e];
        #pragma unroll
        for (int s = 32; s > 0; s >>= 1) v += __shfl_xor(v, s, 64);
        acc[e] = v;
    }
    if (lane == 0) {
        float mx = acc[0];
        #pragma unroll
        for (int e = 1; e < NE; ++e) mx = fmaxf(mx, acc[e]);
        float p[NE], sum = 0.f;
        #pragma unroll
        for (int e = 0; e < NE; ++e) { p[e] = expf(acc[e] - mx); sum += p[e]; }
        float inv = 1.f / sum;
        #pragma unroll
        for (int e = 0; e < NE; ++e) { p[e] *= inv; atomicAdd(&blk_psum[e], p[e]); }
        int i1 = 0; float v1 = p[0];
        #pragma unroll
        for (int e = 1; e < NE; ++e) if (p[e] > v1) { v1 = p[e]; i1 = e; }
        int i2 = -1; float v2 = -1.f;
        #pragma unroll
        for (int e = 0; e < NE; ++e) { if (e == i1) continue; if (p[e] > v2) { v2 = p[e]; i2 = e; } }
        float winv = 1.f / (v1 + v2);
        topi[t] = i1 | (i2 << 8);
        topw[t] = make_float2(v1 * winv, v2 * winv);
    }
    __syncthreads();
    if (tid < NE) psum_part[blockIdx.x * NE + tid] = blk_psum[tid];

    // ---- completion detection: last router block does scatter + finalize ----
    __threadfence();
    if (tid == 0) lastflag = (atomicAdd(rdone, 1) == R1_BLK - 1) ? 1 : 0;
    __syncthreads();
    if (!lastflag) return;
    __threadfence();

    // scatter: 32 chunks of 256 tokens, LDS counters, running bases
    if (tid < NE) rbase[tid] = 0;
    __syncthreads();
    for (int ch = 0; ch < 32; ++ch) {
        int tt = ch * 256 + tid;
        int pk = topi[tt];
        int e1 = pk & 0xff, e2 = (pk >> 8) & 0xff;
        if (tid < NE) lcnt[tid] = 0;
        __syncthreads();
        int p1 = atomicAdd(&lcnt[e1], 1);
        int p2 = atomicAdd(&lcnt[e2], 1);
        __syncthreads();
        if (tid < NE) { cb8[tid] = rbase[tid]; rbase[tid] += lcnt[tid]; }
        __syncthreads();
        elist[e1 * CAP + cb8[e1] + p1] = tt * 2 + 0;
        elist[e2 * CAP + cb8[e2] + p2] = tt * 2 + 1;
        __syncthreads();
    }
    if (tid < NE) ecnt[tid] = rbase[tid];

    // finalize: psum reduce + aux loss + counts (red[] aliases gw)
    float* red = gw;
    int e = tid & 7, b0 = tid >> 3;
    float s = 0.f;
    for (int b = b0; b < R1_BLK; b += 32) s += psum_part[b * NE + e];
    __syncthreads();
    red[tid] = s;
    __syncthreads();
    if (tid < NE) {
        float tot = 0.f;
        #pragma unroll
        for (int j = 0; j < 32; ++j) tot += red[tid + NE * j];
        float P = tot / (float)T_TOK;
        float f = (float)rbase[tid] / (float)(2 * T_TOK);
        parts[tid] = f * P;
        out_tail[1 + tid] = (float)rbase[tid];
    }
    __syncthreads();
    if (tid == 0) {
        float s2 = 0.f;
        for (int i = 0; i < NE; ++i) s2 += parts[i];
        out_tail[0] = (float)NE * s2;
    }
}

// ---------------- GEMM1: 128Mx64N, BK=64, dual output (G,U) ----------------
__global__ __launch_bounds__(256) void gemm1_kernel(
    const unsigned short* __restrict__ xb,   // [T][DM]
    const unsigned short* __restrict__ wgb,  // [NE][DFF][DM]
    const unsigned short* __restrict__ wub,
    const int* __restrict__ elist, const int* __restrict__ ecnt,
    unsigned short* __restrict__ Hbuf)       // [2T][DFF]
{
    int e = blockIdx.z, mt = blockIdx.y, ft = blockIdx.x;
    int ne = ecnt[e];
    if (mt * 128 >= ne) return;

    __shared__ unsigned short As[128 * 64];
    __shared__ unsigned short Gs[64 * 64];
    __shared__ unsigned short Us[64 * 64];
    __shared__ int tsafe[128];
    __shared__ int rawts[128];

    int tid = threadIdx.x;
    if (tid < 128) {
        int pos = mt * 128 + tid;
        int ts0 = elist[e * CAP + mt * 128];
        int ts = (pos < ne) ? elist[e * CAP + pos] : ts0;
        tsafe[tid] = ts >> 1;
        rawts[tid] = (pos < ne) ? ts : -1;
    }
    __syncthreads();

    int wave = tid >> 6, lane = tid & 63;
    int quad = lane >> 4, col = lane & 15;
    int cr = tid >> 3;
    int cl = ((tid & 7) ^ (cr & 7)) * 8;

    const size_t woff = (size_t)e * (size_t)DFF * DM;
    const unsigned short* ap[4];
    #pragma unroll
    for (int j = 0; j < 4; ++j) ap[j] = xb + (size_t)tsafe[j * 32 + cr] * DM + cl;
    const unsigned short* gp[2];
    const unsigned short* up[2];
    #pragma unroll
    for (int j = 0; j < 2; ++j) {
        gp[j] = wgb + woff + (size_t)(ft * 64 + j * 32 + cr) * DM + cl;
        up[j] = wub + woff + (size_t)(ft * 64 + j * 32 + cr) * DM + cl;
    }
    unsigned short* lA = As + wave * 512;
    unsigned short* lG = Gs + wave * 512;
    unsigned short* lU = Us + wave * 512;

    f32x4 accG[2][4], accU[2][4];
    #pragma unroll
    for (int i = 0; i < 2; ++i)
        #pragma unroll
        for (int n = 0; n < 4; ++n) { accG[i][n] = (f32x4){0,0,0,0}; accU[i][n] = (f32x4){0,0,0,0}; }

    for (int k0 = 0; k0 < DM; k0 += 64) {
        __syncthreads();
        #pragma unroll
        for (int j = 0; j < 4; ++j) ASYNC16(ap[j] + k0, lA + j * 2048);
        #pragma unroll
        for (int j = 0; j < 2; ++j) {
            ASYNC16(gp[j] + k0, lG + j * 2048);
            ASYNC16(up[j] + k0, lU + j * 2048);
        }
        __syncthreads();
        #pragma unroll
        for (int ksoff = 0; ksoff < 8; ksoff += 4) {
            bf16x8 a[2], g[4], u[4];
            #pragma unroll
            for (int i = 0; i < 2; ++i) {
                int m = wave * 32 + i * 16 + col;
                a[i] = *(const bf16x8*)&As[m * 64 + ((quad + ksoff) ^ (m & 7)) * 8];
            }
            #pragma unroll
            for (int n = 0; n < 4; ++n) {
                int nb = n * 16 + col;
                int off = nb * 64 + ((quad + ksoff) ^ (nb & 7)) * 8;
                g[n] = *(const bf16x8*)&Gs[off];
                u[n] = *(const bf16x8*)&Us[off];
            }
            #pragma unroll
            for (int i = 0; i < 2; ++i)
                #pragma unroll
                for (int n = 0; n < 4; ++n) {
                    accG[i][n] = __builtin_amdgcn_mfma_f32_16x16x32_bf16(a[i], g[n], accG[i][n], 0, 0, 0);
                    accU[i][n] = __builtin_amdgcn_mfma_f32_16x16x32_bf16(a[i], u[n], accU[i][n], 0, 0, 0);
                }
        }
    }
    #pragma unroll
    for (int i = 0; i < 2; ++i) {
        #pragma unroll
        for (int r = 0; r < 4; ++r) {
            int row = wave * 32 + i * 16 + quad * 4 + r;
            int ts = rawts[row];
            if (ts < 0) continue;
            unsigned short* hr = Hbuf + (size_t)ts * DFF + ft * 64 + col;
            #pragma unroll
            for (int n = 0; n < 4; ++n) {
                float gg = accG[i][n][r], uu = accU[i][n][r];
                float h = (gg / (1.f + expf(-gg))) * uu;
                hr[n * 16] = f2bf(h);
            }
        }
    }
}

// ---------------- GEMM2: 128Mx128N, BK=64 -> eo (bf16, unweighted, no atomics) --------
__global__ __launch_bounds__(256) void gemm2_kernel(
    const unsigned short* __restrict__ Hbuf, // [2T][DFF]
    const unsigned short* __restrict__ wdb,  // [NE][DM][DFF]
    const int* __restrict__ elist, const int* __restrict__ ecnt,
    unsigned short* __restrict__ eo)         // [2T][DM]
{
    int e = blockIdx.z, mt = blockIdx.y, dt = blockIdx.x;
    int ne = ecnt[e];
    if (mt * 128 >= ne) return;

    __shared__ unsigned short As[128 * 64];
    __shared__ unsigned short Bs[128 * 64];
    __shared__ int tsafe[128];
    __shared__ int rawts[128];

    int tid = threadIdx.x;
    if (tid < 128) {
        int pos = mt * 128 + tid;
        int ts0 = elist[e * CAP + mt * 128];
        int ts = (pos < ne) ? elist[e * CAP + pos] : ts0;
        tsafe[tid] = ts;
        rawts[tid] = (pos < ne) ? ts : -1;
    }
    __syncthreads();

    int wave = tid >> 6, lane = tid & 63;
    int quad = lane >> 4, col = lane & 15;
    int wr = (wave >> 1) * 64, wc = (wave & 1) * 64;
    int cr = tid >> 3;
    int cl = ((tid & 7) ^ (cr & 7)) * 8;

    const size_t woff = (size_t)e * (size_t)DM * DFF;
    const unsigned short* ap[4];
    const unsigned short* bp[4];
    #pragma unroll
    for (int j = 0; j < 4; ++j) {
        ap[j] = Hbuf + (size_t)tsafe[j * 32 + cr] * DFF + cl;
        bp[j] = wdb + woff + (size_t)(dt * 128 + j * 32 + cr) * DFF + cl;
    }
    unsigned short* lA = As + wave * 512;
    unsigned short* lB = Bs + wave * 512;

    f32x4 acc[4][4];
    #pragma unroll
    for (int i = 0; i < 4; ++i)
        #pragma unroll
        for (int n = 0; n < 4; ++n) acc[i][n] = (f32x4){0,0,0,0};

    for (int k0 = 0; k0 < DFF; k0 += 64) {
        __syncthreads();
        #pragma unroll
        for (int j = 0; j < 4; ++j) {
            ASYNC16(ap[j] + k0, lA + j * 2048);
            ASYNC16(bp[j] + k0, lB + j * 2048);
        }
        __syncthreads();
        #pragma unroll
        for (int ksoff = 0; ksoff < 8; ksoff += 4) {
            bf16x8 a[4], b[4];
            #pragma unroll
            for (int i = 0; i < 4; ++i) {
                int m = wr + i * 16 + col;
                a[i] = *(const bf16x8*)&As[m * 64 + ((quad + ksoff) ^ (m & 7)) * 8];
            }
            #pragma unroll
            for (int n = 0; n < 4; ++n) {
                int nb = wc + n * 16 + col;
                b[n] = *(const bf16x8*)&Bs[nb * 64 + ((quad + ksoff) ^ (nb & 7)) * 8];
            }
            #pragma unroll
            for (int i = 0; i < 4; ++i)
                #pragma unroll
                for (int n = 0; n < 4; ++n)
                    acc[i][n] = __builtin_amdgcn_mfma_f32_16x16x32_bf16(a[i], b[n], acc[i][n], 0, 0, 0);
        }
    }
    #pragma unroll
    for (int i = 0; i < 4; ++i) {
        #pragma unroll
        for (int r = 0; r < 4; ++r) {
            int row = wr + i * 16 + quad * 4 + r;
            int ts = rawts[row];
            if (ts < 0) continue;
            unsigned short* er = eo + (size_t)ts * DM + dt * 128 + wc + col;
            #pragma unroll
            for (int n = 0; n < 4; ++n)
                er[n * 16] = f2bf(acc[i][n][r]);
        }
    }
}

// ---------------- combine: out[t] = w1*eo[2t] + w2*eo[2t+1] ----------------
__global__ __launch_bounds__(256) void combine_kernel(
    const unsigned short* __restrict__ eo, const float2* __restrict__ topw,
    float* __restrict__ out)
{
    int idx = blockIdx.x * 256 + threadIdx.x;
    int t = idx >> 7;
    int c = (idx & 127) << 3;
    float2 w = topw[t];
    const unsigned short* e0 = eo + (size_t)(t * 2) * DM + c;
    ushort4 a0 = *(const ushort4*)e0;
    ushort4 a1 = *(const ushort4*)(e0 + 4);
    ushort4 b0 = *(const ushort4*)(e0 + DM);
    ushort4 b1 = *(const ushort4*)(e0 + DM + 4);
    float* orow = out + (size_t)t * DM + c;
    float4 o0, o1;
    o0.x = w.x * bf2f(a0.x) + w.y * bf2f(b0.x);
    o0.y = w.x * bf2f(a0.y) + w.y * bf2f(b0.y);
    o0.z = w.x * bf2f(a0.z) + w.y * bf2f(b0.z);
    o0.w = w.x * bf2f(a0.w) + w.y * bf2f(b0.w);
    o1.x = w.x * bf2f(a1.x) + w.y * bf2f(b1.x);
    o1.y = w.x * bf2f(a1.y) + w.y * bf2f(b1.y);
    o1.z = w.x * bf2f(a1.z) + w.y * bf2f(b1.z);
    o1.w = w.x * bf2f(a1.w) + w.y * bf2f(b1.w);
    *(float4*)orow = o0;
    *(float4*)(orow + 4) = o1;
}

extern "C" void kernel_launch(void* const* d_in, const int* in_sizes, int n_in,
                              void* d_out, int out_size, void* d_ws, size_t ws_size,
                              hipStream_t stream) {
    const float* x      = (const float*)d_in[0];
    const float* gate_w = (const float*)d_in[1];
    const float* w_gate = (const float*)d_in[2];
    const float* w_up   = (const float*)d_in[3];
    const float* w_down = (const float*)d_in[4];
    float* out = (float*)d_out;

    char* p = (char*)d_ws;
    unsigned short* xb   = (unsigned short*)p; p += (size_t)T_TOK * DM * 2;
    unsigned short* wgb  = (unsigned short*)p; p += (size_t)NE * DFF * DM * 2;
    unsigned short* wub  = (unsigned short*)p; p += (size_t)NE * DFF * DM * 2;
    unsigned short* wdb  = (unsigned short*)p; p += (size_t)NE * DM * DFF * 2;
    unsigned short* Hbuf = (unsigned short*)p; p += (size_t)2 * T_TOK * DFF * 2;
    int*   elist = (int*)p;   p += (size_t)NE * CAP * 4;
    int*   ecnt  = (int*)p;   p += NE * 4;
    int*   topi  = (int*)p;   p += (size_t)T_TOK * 4;
    float2* topw = (float2*)p; p += (size_t)T_TOK * 8;
    float* psum_part = (float*)p; p += (size_t)R1_BLK * NE * 4;
    int*   rdone = (int*)p;   p += 64;
    // eo aliases wgb+wub (dead after gemm1): [2T][DM] bf16
    unsigned short* eo = wgb;

    hipMemsetAsync(rdone, 0, 64, stream);

    mega_kernel<<<R1_BLK + CVT_BLK, 256, 0, stream>>>(
        x, gate_w, w_gate, w_up, w_down, wgb, wub, wdb,
        xb, topi, topw, psum_part, elist, ecnt, rdone,
        out + (size_t)T_TOK * DM);

    gemm1_kernel<<<dim3(DFF / 64, CAP / 128, NE), 256, 0, stream>>>(xb, wgb, wub, elist, ecnt, Hbuf);
    gemm2_kernel<<<dim3(DM / 128, CAP / 128, NE), 256, 0, stream>>>(Hbuf, wdb, elist, ecnt, eo);
    combine_kernel<<<T_TOK * DM / 8 / 256, 256, 0, stream>>>(eo, topw, out);
}

// Round 6
// 347.494 us; speedup vs baseline: 1.4316x; 1.4316x over previous
//
#include <hip/hip_runtime.h>

// MoE: T=8192, D_MODEL=1024, D_FF=1024, E=8, top-2.
// Router fp32; FFN bf16 MFMA (m97-style async staging + XOR swizzle).
// R6: revert R5's fence-poisoned mega. pre_kernel = cvt3 || router (independent,
// NO cross-block comms, no fences). scatter+finalize = own 1-block kernel
// (kernel boundary = free coherence).

#define T_TOK   8192
#define DM      1024
#define DFF     1024
#define NE      8
#define CAP     16384
#define R1_BLK  (T_TOK / 4)    // 2048 router blocks
#define CVT_BLK 2048           // conversion blocks

typedef __attribute__((ext_vector_type(8))) short bf16x8;
typedef __attribute__((ext_vector_type(4))) float f32x4;

#define ASYNC16(gp, lp) __builtin_amdgcn_global_load_lds( \
    (const __attribute__((address_space(1))) unsigned int*)(gp), \
    (__attribute__((address_space(3))) unsigned int*)(lp), 16, 0, 0)

__device__ __forceinline__ unsigned short f2bf(float f) {
    union { float f; unsigned u; } c; c.f = f;
    unsigned r = c.u + 0x7fffu + ((c.u >> 16) & 1u);
    return (unsigned short)(r >> 16);
}
__device__ __forceinline__ float bf2f(unsigned short h) {
    union { unsigned u; float f; } c; c.u = ((unsigned)h) << 16;
    return c.f;
}

// ---------------- pre: cvt3 || router (disjoint work, zero cross-block comms) --------
__global__ __launch_bounds__(256) void pre_kernel(
    const float* __restrict__ x, const float* __restrict__ gate_w,
    const float* __restrict__ s0, const float* __restrict__ s1, const float* __restrict__ s2,
    unsigned short* __restrict__ d0, unsigned short* __restrict__ d1, unsigned short* __restrict__ d2,
    unsigned short* __restrict__ xb,
    int* __restrict__ topi, float2* __restrict__ topw, float* __restrict__ psum_part)
{
    int tid = threadIdx.x;

    if (blockIdx.x >= R1_BLK) {
        // ---- cvt role: 3 weight tensors, 12 float4 per thread, grid-strided ----
        int base = (blockIdx.x - R1_BLK) * 256 + tid;
        #pragma unroll
        for (int it = 0; it < 12; ++it) {
            int idx = base + it * (CVT_BLK * 256);
            int seg = idx >> 21;                    // 2^21 float4 per tensor
            int off = (idx & ((1 << 21) - 1)) * 4;
            const float* s = (seg == 0) ? s0 : (seg == 1) ? s1 : s2;
            unsigned short* d = (seg == 0) ? d0 : (seg == 1) ? d1 : d2;
            float4 v = *(const float4*)(s + off);
            ushort4 o;
            o.x = f2bf(v.x); o.y = f2bf(v.y); o.z = f2bf(v.z); o.w = f2bf(v.w);
            *(ushort4*)(d + off) = o;
        }
        return;
    }

    // ---- router role (fp32, per-block partials only) ----
    __shared__ float gw[NE * DM];
    __shared__ float blk_psum[NE];

    for (int i = tid; i < NE * DM; i += 256) gw[i] = gate_w[i];
    if (tid < NE) blk_psum[tid] = 0.f;
    __syncthreads();

    int wv = tid >> 6, lane = tid & 63;
    int t = blockIdx.x * 4 + wv;

    float acc[NE];
    #pragma unroll
    for (int e = 0; e < NE; ++e) acc[e] = 0.f;
    const float* xr = x + (size_t)t * DM;
    unsigned short* xbr = xb + (size_t)t * DM;
    #pragma unroll 4
    for (int i = 0; i < DM / 64; ++i) {
        float xv = xr[i * 64 + lane];
        xbr[i * 64 + lane] = f2bf(xv);
        #pragma unroll
        for (int e = 0; e < NE; ++e)
            acc[e] += xv * gw[e * DM + i * 64 + lane];
    }
    #pragma unroll
    for (int e = 0; e < NE; ++e) {
        float v = acc[e];
        #pragma unroll
        for (int s = 32; s > 0; s >>= 1) v += __shfl_xor(v, s, 64);
        acc[e] = v;
    }
    if (lane == 0) {
        float mx = acc[0];
        #pragma unroll
        for (int e = 1; e < NE; ++e) mx = fmaxf(mx, acc[e]);
        float p[NE], sum = 0.f;
        #pragma unroll
        for (int e = 0; e < NE; ++e) { p[e] = expf(acc[e] - mx); sum += p[e]; }
        float inv = 1.f / sum;
        #pragma unroll
        for (int e = 0; e < NE; ++e) { p[e] *= inv; atomicAdd(&blk_psum[e], p[e]); }
        int i1 = 0; float v1 = p[0];
        #pragma unroll
        for (int e = 1; e < NE; ++e) if (p[e] > v1) { v1 = p[e]; i1 = e; }
        int i2 = -1; float v2 = -1.f;
        #pragma unroll
        for (int e = 0; e < NE; ++e) { if (e == i1) continue; if (p[e] > v2) { v2 = p[e]; i2 = e; } }
        float winv = 1.f / (v1 + v2);
        topi[t] = i1 | (i2 << 8);
        topw[t] = make_float2(v1 * winv, v2 * winv);
    }
    __syncthreads();
    if (tid < NE) psum_part[blockIdx.x * NE + tid] = blk_psum[tid];
}

// ---------------- scatfin: scatter + finalize, 1 block x 1024 threads ----------------
__global__ __launch_bounds__(1024) void scatfin_kernel(
    const int* __restrict__ topi, const float* __restrict__ psum_part,
    int* __restrict__ elist, int* __restrict__ ecnt, float* __restrict__ out_tail)
{
    __shared__ int lcnt[NE], rbase[NE], cb8[NE];
    __shared__ float parts[NE];
    __shared__ float red[1024];
    int tid = threadIdx.x;

    if (tid < NE) rbase[tid] = 0;
    __syncthreads();
    #pragma unroll
    for (int ch = 0; ch < T_TOK / 1024; ++ch) {
        int tt = ch * 1024 + tid;
        int pk = topi[tt];
        int e1 = pk & 0xff, e2 = (pk >> 8) & 0xff;
        if (tid < NE) lcnt[tid] = 0;
        __syncthreads();
        int p1 = atomicAdd(&lcnt[e1], 1);
        int p2 = atomicAdd(&lcnt[e2], 1);
        __syncthreads();
        if (tid < NE) { cb8[tid] = rbase[tid]; rbase[tid] += lcnt[tid]; }
        __syncthreads();
        elist[e1 * CAP + cb8[e1] + p1] = tt * 2 + 0;
        elist[e2 * CAP + cb8[e2] + p2] = tt * 2 + 1;
        __syncthreads();
    }
    if (tid < NE) ecnt[tid] = rbase[tid];

    // finalize: psum reduce + aux loss + counts
    int e = tid & 7, b0 = tid >> 3;     // 128 threads per expert
    float s = 0.f;
    for (int b = b0; b < R1_BLK; b += 128) s += psum_part[b * NE + e];
    red[tid] = s;
    __syncthreads();
    if (tid < NE) {
        float tot = 0.f;
        #pragma unroll
        for (int j = 0; j < 128; ++j) tot += red[tid + NE * j];
        float P = tot / (float)T_TOK;
        float f = (float)rbase[tid] / (float)(2 * T_TOK);
        parts[tid] = f * P;
        out_tail[1 + tid] = (float)rbase[tid];
    }
    __syncthreads();
    if (tid == 0) {
        float s2 = 0.f;
        for (int i = 0; i < NE; ++i) s2 += parts[i];
        out_tail[0] = (float)NE * s2;
    }
}

// ---------------- GEMM1: 128Mx64N, BK=64, dual output (G,U) ----------------
__global__ __launch_bounds__(256) void gemm1_kernel(
    const unsigned short* __restrict__ xb,   // [T][DM]
    const unsigned short* __restrict__ wgb,  // [NE][DFF][DM]
    const unsigned short* __restrict__ wub,
    const int* __restrict__ elist, const int* __restrict__ ecnt,
    unsigned short* __restrict__ Hbuf)       // [2T][DFF]
{
    int e = blockIdx.z, mt = blockIdx.y, ft = blockIdx.x;
    int ne = ecnt[e];
    if (mt * 128 >= ne) return;

    __shared__ unsigned short As[128 * 64];
    __shared__ unsigned short Gs[64 * 64];
    __shared__ unsigned short Us[64 * 64];
    __shared__ int tsafe[128];
    __shared__ int rawts[128];

    int tid = threadIdx.x;
    if (tid < 128) {
        int pos = mt * 128 + tid;
        int ts0 = elist[e * CAP + mt * 128];
        int ts = (pos < ne) ? elist[e * CAP + pos] : ts0;
        tsafe[tid] = ts >> 1;
        rawts[tid] = (pos < ne) ? ts : -1;
    }
    __syncthreads();

    int wave = tid >> 6, lane = tid & 63;
    int quad = lane >> 4, col = lane & 15;
    int cr = tid >> 3;
    int cl = ((tid & 7) ^ (cr & 7)) * 8;

    const size_t woff = (size_t)e * (size_t)DFF * DM;
    const unsigned short* ap[4];
    #pragma unroll
    for (int j = 0; j < 4; ++j) ap[j] = xb + (size_t)tsafe[j * 32 + cr] * DM + cl;
    const unsigned short* gp[2];
    const unsigned short* up[2];
    #pragma unroll
    for (int j = 0; j < 2; ++j) {
        gp[j] = wgb + woff + (size_t)(ft * 64 + j * 32 + cr) * DM + cl;
        up[j] = wub + woff + (size_t)(ft * 64 + j * 32 + cr) * DM + cl;
    }
    unsigned short* lA = As + wave * 512;
    unsigned short* lG = Gs + wave * 512;
    unsigned short* lU = Us + wave * 512;

    f32x4 accG[2][4], accU[2][4];
    #pragma unroll
    for (int i = 0; i < 2; ++i)
        #pragma unroll
        for (int n = 0; n < 4; ++n) { accG[i][n] = (f32x4){0,0,0,0}; accU[i][n] = (f32x4){0,0,0,0}; }

    for (int k0 = 0; k0 < DM; k0 += 64) {
        __syncthreads();
        #pragma unroll
        for (int j = 0; j < 4; ++j) ASYNC16(ap[j] + k0, lA + j * 2048);
        #pragma unroll
        for (int j = 0; j < 2; ++j) {
            ASYNC16(gp[j] + k0, lG + j * 2048);
            ASYNC16(up[j] + k0, lU + j * 2048);
        }
        __syncthreads();
        #pragma unroll
        for (int ksoff = 0; ksoff < 8; ksoff += 4) {
            bf16x8 a[2], g[4], u[4];
            #pragma unroll
            for (int i = 0; i < 2; ++i) {
                int m = wave * 32 + i * 16 + col;
                a[i] = *(const bf16x8*)&As[m * 64 + ((quad + ksoff) ^ (m & 7)) * 8];
            }
            #pragma unroll
            for (int n = 0; n < 4; ++n) {
                int nb = n * 16 + col;
                int off = nb * 64 + ((quad + ksoff) ^ (nb & 7)) * 8;
                g[n] = *(const bf16x8*)&Gs[off];
                u[n] = *(const bf16x8*)&Us[off];
            }
            #pragma unroll
            for (int i = 0; i < 2; ++i)
                #pragma unroll
                for (int n = 0; n < 4; ++n) {
                    accG[i][n] = __builtin_amdgcn_mfma_f32_16x16x32_bf16(a[i], g[n], accG[i][n], 0, 0, 0);
                    accU[i][n] = __builtin_amdgcn_mfma_f32_16x16x32_bf16(a[i], u[n], accU[i][n], 0, 0, 0);
                }
        }
    }
    #pragma unroll
    for (int i = 0; i < 2; ++i) {
        #pragma unroll
        for (int r = 0; r < 4; ++r) {
            int row = wave * 32 + i * 16 + quad * 4 + r;
            int ts = rawts[row];
            if (ts < 0) continue;
            unsigned short* hr = Hbuf + (size_t)ts * DFF + ft * 64 + col;
            #pragma unroll
            for (int n = 0; n < 4; ++n) {
                float gg = accG[i][n][r], uu = accU[i][n][r];
                float h = (gg / (1.f + expf(-gg))) * uu;
                hr[n * 16] = f2bf(h);
            }
        }
    }
}

// ---------------- GEMM2: 128Mx128N, BK=64 -> eo (bf16, unweighted, no atomics) --------
__global__ __launch_bounds__(256) void gemm2_kernel(
    const unsigned short* __restrict__ Hbuf, // [2T][DFF]
    const unsigned short* __restrict__ wdb,  // [NE][DM][DFF]
    const int* __restrict__ elist, const int* __restrict__ ecnt,
    unsigned short* __restrict__ eo)         // [2T][DM]
{
    int e = blockIdx.z, mt = blockIdx.y, dt = blockIdx.x;
    int ne = ecnt[e];
    if (mt * 128 >= ne) return;

    __shared__ unsigned short As[128 * 64];
    __shared__ unsigned short Bs[128 * 64];
    __shared__ int tsafe[128];
    __shared__ int rawts[128];

    int tid = threadIdx.x;
    if (tid < 128) {
        int pos = mt * 128 + tid;
        int ts0 = elist[e * CAP + mt * 128];
        int ts = (pos < ne) ? elist[e * CAP + pos] : ts0;
        tsafe[tid] = ts;
        rawts[tid] = (pos < ne) ? ts : -1;
    }
    __syncthreads();

    int wave = tid >> 6, lane = tid & 63;
    int quad = lane >> 4, col = lane & 15;
    int wr = (wave >> 1) * 64, wc = (wave & 1) * 64;
    int cr = tid >> 3;
    int cl = ((tid & 7) ^ (cr & 7)) * 8;

    const size_t woff = (size_t)e * (size_t)DM * DFF;
    const unsigned short* ap[4];
    const unsigned short* bp[4];
    #pragma unroll
    for (int j = 0; j < 4; ++j) {
        ap[j] = Hbuf + (size_t)tsafe[j * 32 + cr] * DFF + cl;
        bp[j] = wdb + woff + (size_t)(dt * 128 + j * 32 + cr) * DFF + cl;
    }
    unsigned short* lA = As + wave * 512;
    unsigned short* lB = Bs + wave * 512;

    f32x4 acc[4][4];
    #pragma unroll
    for (int i = 0; i < 4; ++i)
        #pragma unroll
        for (int n = 0; n < 4; ++n) acc[i][n] = (f32x4){0,0,0,0};

    for (int k0 = 0; k0 < DFF; k0 += 64) {
        __syncthreads();
        #pragma unroll
        for (int j = 0; j < 4; ++j) {
            ASYNC16(ap[j] + k0, lA + j * 2048);
            ASYNC16(bp[j] + k0, lB + j * 2048);
        }
        __syncthreads();
        #pragma unroll
        for (int ksoff = 0; ksoff < 8; ksoff += 4) {
            bf16x8 a[4], b[4];
            #pragma unroll
            for (int i = 0; i < 4; ++i) {
                int m = wr + i * 16 + col;
                a[i] = *(const bf16x8*)&As[m * 64 + ((quad + ksoff) ^ (m & 7)) * 8];
            }
            #pragma unroll
            for (int n = 0; n < 4; ++n) {
                int nb = wc + n * 16 + col;
                b[n] = *(const bf16x8*)&Bs[nb * 64 + ((quad + ksoff) ^ (nb & 7)) * 8];
            }
            #pragma unroll
            for (int i = 0; i < 4; ++i)
                #pragma unroll
                for (int n = 0; n < 4; ++n)
                    acc[i][n] = __builtin_amdgcn_mfma_f32_16x16x32_bf16(a[i], b[n], acc[i][n], 0, 0, 0);
        }
    }
    #pragma unroll
    for (int i = 0; i < 4; ++i) {
        #pragma unroll
        for (int r = 0; r < 4; ++r) {
            int row = wr + i * 16 + quad * 4 + r;
            int ts = rawts[row];
            if (ts < 0) continue;
            unsigned short* er = eo + (size_t)ts * DM + dt * 128 + wc + col;
            #pragma unroll
            for (int n = 0; n < 4; ++n)
                er[n * 16] = f2bf(acc[i][n][r]);
        }
    }
}

// ---------------- combine: out[t] = w1*eo[2t] + w2*eo[2t+1] ----------------
__global__ __launch_bounds__(256) void combine_kernel(
    const unsigned short* __restrict__ eo, const float2* __restrict__ topw,
    float* __restrict__ out)
{
    int idx = blockIdx.x * 256 + threadIdx.x;
    int t = idx >> 7;
    int c = (idx & 127) << 3;
    float2 w = topw[t];
    const unsigned short* e0 = eo + (size_t)(t * 2) * DM + c;
    ushort4 a0 = *(const ushort4*)e0;
    ushort4 a1 = *(const ushort4*)(e0 + 4);
    ushort4 b0 = *(const ushort4*)(e0 + DM);
    ushort4 b1 = *(const ushort4*)(e0 + DM + 4);
    float* orow = out + (size_t)t * DM + c;
    float4 o0, o1;
    o0.x = w.x * bf2f(a0.x) + w.y * bf2f(b0.x);
    o0.y = w.x * bf2f(a0.y) + w.y * bf2f(b0.y);
    o0.z = w.x * bf2f(a0.z) + w.y * bf2f(b0.z);
    o0.w = w.x * bf2f(a0.w) + w.y * bf2f(b0.w);
    o1.x = w.x * bf2f(a1.x) + w.y * bf2f(b1.x);
    o1.y = w.x * bf2f(a1.y) + w.y * bf2f(b1.y);
    o1.z = w.x * bf2f(a1.z) + w.y * bf2f(b1.z);
    o1.w = w.x * bf2f(a1.w) + w.y * bf2f(b1.w);
    *(float4*)orow = o0;
    *(float4*)(orow + 4) = o1;
}

extern "C" void kernel_launch(void* const* d_in, const int* in_sizes, int n_in,
                              void* d_out, int out_size, void* d_ws, size_t ws_size,
                              hipStream_t stream) {
    const float* x      = (const float*)d_in[0];
    const float* gate_w = (const float*)d_in[1];
    const float* w_gate = (const float*)d_in[2];
    const float* w_up   = (const float*)d_in[3];
    const float* w_down = (const float*)d_in[4];
    float* out = (float*)d_out;

    char* p = (char*)d_ws;
    unsigned short* xb   = (unsigned short*)p; p += (size_t)T_TOK * DM * 2;
    unsigned short* wgb  = (unsigned short*)p; p += (size_t)NE * DFF * DM * 2;
    unsigned short* wub  = (unsigned short*)p; p += (size_t)NE * DFF * DM * 2;
    unsigned short* wdb  = (unsigned short*)p; p += (size_t)NE * DM * DFF * 2;
    unsigned short* Hbuf = (unsigned short*)p; p += (size_t)2 * T_TOK * DFF * 2;
    int*   elist = (int*)p;   p += (size_t)NE * CAP * 4;
    int*   ecnt  = (int*)p;   p += NE * 4;
    int*   topi  = (int*)p;   p += (size_t)T_TOK * 4;
    float2* topw = (float2*)p; p += (size_t)T_TOK * 8;
    float* psum_part = (float*)p; p += (size_t)R1_BLK * NE * 4;
    // eo aliases wgb+wub (dead after gemm1): [2T][DM] bf16
    unsigned short* eo = wgb;

    pre_kernel<<<R1_BLK + CVT_BLK, 256, 0, stream>>>(
        x, gate_w, w_gate, w_up, w_down, wgb, wub, wdb,
        xb, topi, topw, psum_part);
    scatfin_kernel<<<1, 1024, 0, stream>>>(topi, psum_part, elist, ecnt,
                                           out + (size_t)T_TOK * DM);
    gemm1_kernel<<<dim3(DFF / 64, CAP / 128, NE), 256, 0, stream>>>(xb, wgb, wub, elist, ecnt, Hbuf);
    gemm2_kernel<<<dim3(DM / 128, CAP / 128, NE), 256, 0, stream>>>(Hbuf, wdb, elist, ecnt, eo);
    combine_kernel<<<T_TOK * DM / 8 / 256, 256, 0, stream>>>(eo, topw, out);
}

// Round 7
// 334.732 us; speedup vs baseline: 1.4861x; 1.0381x over previous
//
#include <hip/hip_runtime.h>

// MoE: T=8192, D_MODEL=1024, D_FF=1024, E=8, top-2.
// Router fp32; FFN bf16 MFMA (m97-style async staging + XOR swizzle).
// R7: (1) pre = router/cvt interleaved by blockIdx&1 (true overlap).
//     (2) slot-ordered H/eo: scatfin computes dense slot rows (ebase prefix);
//         gemm2 reads/writes fully affine; combine gathers via cidx[t].

#define T_TOK   8192
#define DM      1024
#define DFF     1024
#define NE      8
#define TOTS    (2 * T_TOK)    // 16384 slots
#define R1_BLK  2048           // router blocks (4 tokens each)
#define CVT_BLK 2048           // conversion blocks

typedef __attribute__((ext_vector_type(8))) short bf16x8;
typedef __attribute__((ext_vector_type(4))) float f32x4;

#define ASYNC16(gp, lp) __builtin_amdgcn_global_load_lds( \
    (const __attribute__((address_space(1))) unsigned int*)(gp), \
    (__attribute__((address_space(3))) unsigned int*)(lp), 16, 0, 0)

__device__ __forceinline__ unsigned short f2bf(float f) {
    union { float f; unsigned u; } c; c.f = f;
    unsigned r = c.u + 0x7fffu + ((c.u >> 16) & 1u);
    return (unsigned short)(r >> 16);
}
__device__ __forceinline__ float bf2f(unsigned short h) {
    union { unsigned u; float f; } c; c.u = ((unsigned)h) << 16;
    return c.f;
}

// ---------------- pre: router (even blocks) || cvt3 (odd blocks) ----------------
__global__ __launch_bounds__(256) void pre_kernel(
    const float* __restrict__ x, const float* __restrict__ gate_w,
    const float* __restrict__ s0, const float* __restrict__ s1, const float* __restrict__ s2,
    unsigned short* __restrict__ d0, unsigned short* __restrict__ d1, unsigned short* __restrict__ d2,
    unsigned short* __restrict__ xb,
    int* __restrict__ topi, float2* __restrict__ topw, float* __restrict__ psum_part)
{
    int tid = threadIdx.x;
    int sub = blockIdx.x >> 1;

    if (blockIdx.x & 1) {
        // ---- cvt role: 3 weight tensors, 12 float4 per thread ----
        int base = sub * 256 + tid;
        #pragma unroll
        for (int it = 0; it < 12; ++it) {
            int idx = base + it * (CVT_BLK * 256);
            int seg = idx >> 21;                    // 2^21 float4 per tensor
            int off = (idx & ((1 << 21) - 1)) * 4;
            const float* s = (seg == 0) ? s0 : (seg == 1) ? s1 : s2;
            unsigned short* d = (seg == 0) ? d0 : (seg == 1) ? d1 : d2;
            float4 v = *(const float4*)(s + off);
            ushort4 o;
            o.x = f2bf(v.x); o.y = f2bf(v.y); o.z = f2bf(v.z); o.w = f2bf(v.w);
            *(ushort4*)(d + off) = o;
        }
        return;
    }

    // ---- router role (fp32, per-block partials only) ----
    __shared__ float gw[NE * DM];
    __shared__ float blk_psum[NE];

    for (int i = tid; i < NE * DM; i += 256) gw[i] = gate_w[i];
    if (tid < NE) blk_psum[tid] = 0.f;
    __syncthreads();

    int wv = tid >> 6, lane = tid & 63;
    int t = sub * 4 + wv;

    float acc[NE];
    #pragma unroll
    for (int e = 0; e < NE; ++e) acc[e] = 0.f;
    const float* xr = x + (size_t)t * DM;
    unsigned short* xbr = xb + (size_t)t * DM;
    #pragma unroll 4
    for (int i = 0; i < DM / 64; ++i) {
        float xv = xr[i * 64 + lane];
        xbr[i * 64 + lane] = f2bf(xv);
        #pragma unroll
        for (int e = 0; e < NE; ++e)
            acc[e] += xv * gw[e * DM + i * 64 + lane];
    }
    #pragma unroll
    for (int e = 0; e < NE; ++e) {
        float v = acc[e];
        #pragma unroll
        for (int s = 32; s > 0; s >>= 1) v += __shfl_xor(v, s, 64);
        acc[e] = v;
    }
    if (lane == 0) {
        float mx = acc[0];
        #pragma unroll
        for (int e = 1; e < NE; ++e) mx = fmaxf(mx, acc[e]);
        float p[NE], sum = 0.f;
        #pragma unroll
        for (int e = 0; e < NE; ++e) { p[e] = expf(acc[e] - mx); sum += p[e]; }
        float inv = 1.f / sum;
        #pragma unroll
        for (int e = 0; e < NE; ++e) { p[e] *= inv; atomicAdd(&blk_psum[e], p[e]); }
        int i1 = 0; float v1 = p[0];
        #pragma unroll
        for (int e = 1; e < NE; ++e) if (p[e] > v1) { v1 = p[e]; i1 = e; }
        int i2 = -1; float v2 = -1.f;
        #pragma unroll
        for (int e = 0; e < NE; ++e) { if (e == i1) continue; if (p[e] > v2) { v2 = p[e]; i2 = e; } }
        float winv = 1.f / (v1 + v2);
        topi[t] = i1 | (i2 << 8);
        topw[t] = make_float2(v1 * winv, v2 * winv);
    }
    __syncthreads();
    if (tid < NE) psum_part[sub * NE + tid] = blk_psum[tid];
}

// ---------------- scatfin: slot assignment (dense rows) + finalize ----------------
__global__ __launch_bounds__(1024) void scatfin_kernel(
    const int* __restrict__ topi, const float* __restrict__ psum_part,
    int* __restrict__ elist, int2* __restrict__ cidx,
    int* __restrict__ ecnt, int* __restrict__ ebaseg, float* __restrict__ out_tail)
{
    __shared__ int lcnt[NE], run[NE], cb[NE], ebase[NE];
    __shared__ float parts[NE];
    __shared__ float red[1024];
    int tid = threadIdx.x;

    if (tid < NE) run[tid] = 0;
    __syncthreads();
    // pass 1: within-expert positions
    #pragma unroll
    for (int ch = 0; ch < T_TOK / 1024; ++ch) {
        int tt = ch * 1024 + tid;
        int pk = topi[tt];
        int e1 = pk & 0xff, e2 = (pk >> 8) & 0xff;
        if (tid < NE) lcnt[tid] = 0;
        __syncthreads();
        int p1 = atomicAdd(&lcnt[e1], 1);
        int p2 = atomicAdd(&lcnt[e2], 1);
        __syncthreads();
        if (tid < NE) { cb[tid] = run[tid]; run[tid] += lcnt[tid]; }
        __syncthreads();
        cidx[tt] = make_int2(cb[e1] + p1, cb[e2] + p2);
    }
    __syncthreads();
    if (tid == 0) {
        int s = 0;
        for (int e = 0; e < NE; ++e) { ebase[e] = s; s += run[e]; }
    }
    __syncthreads();
    // pass 2: global slot rows + elist (slot -> token)
    #pragma unroll
    for (int ch = 0; ch < T_TOK / 1024; ++ch) {
        int tt = ch * 1024 + tid;
        int pk = topi[tt];
        int e1 = pk & 0xff, e2 = (pk >> 8) & 0xff;
        int2 pp = cidx[tt];
        int r1 = ebase[e1] + pp.x, r2 = ebase[e2] + pp.y;
        elist[r1] = tt;
        elist[r2] = tt;
        cidx[tt] = make_int2(r1, r2);
    }
    if (tid < NE) { ecnt[tid] = run[tid]; ebaseg[tid] = ebase[tid]; }

    // finalize: psum reduce + aux loss + counts
    int e = tid & 7, b0 = tid >> 3;
    float s = 0.f;
    for (int b = b0; b < R1_BLK; b += 128) s += psum_part[b * NE + e];
    red[tid] = s;
    __syncthreads();
    if (tid < NE) {
        float tot = 0.f;
        #pragma unroll
        for (int j = 0; j < 128; ++j) tot += red[tid + NE * j];
        float P = tot / (float)T_TOK;
        float f = (float)run[tid] / (float)(2 * T_TOK);
        parts[tid] = f * P;
        out_tail[1 + tid] = (float)run[tid];
    }
    __syncthreads();
    if (tid == 0) {
        float s2 = 0.f;
        for (int i = 0; i < NE; ++i) s2 += parts[i];
        out_tail[0] = (float)NE * s2;
    }
}

// ---------------- GEMM1: 128Mx64N, BK=64, dual output (G,U); H in slot order ------
__global__ __launch_bounds__(256) void gemm1_kernel(
    const unsigned short* __restrict__ xb,   // [T][DM]
    const unsigned short* __restrict__ wgb,  // [NE][DFF][DM]
    const unsigned short* __restrict__ wub,
    const int* __restrict__ elist, const int* __restrict__ ecnt,
    const int* __restrict__ ebaseg,
    unsigned short* __restrict__ Hbuf)       // [TOTS][DFF] slot-ordered
{
    int e = blockIdx.z, mt = blockIdx.y, ft = blockIdx.x;
    int ne = ecnt[e];
    if (mt * 128 >= ne) return;
    int base = ebaseg[e];

    __shared__ unsigned short As[128 * 64];
    __shared__ unsigned short Gs[64 * 64];
    __shared__ unsigned short Us[64 * 64];
    __shared__ int tok[128];

    int tid = threadIdx.x;
    if (tid < 128) {
        int slot = base + mt * 128 + tid;
        tok[tid] = elist[min(slot, TOTS - 1)];
    }
    __syncthreads();

    int wave = tid >> 6, lane = tid & 63;
    int quad = lane >> 4, col = lane & 15;
    int cr = tid >> 3;
    int cl = ((tid & 7) ^ (cr & 7)) * 8;

    const size_t woff = (size_t)e * (size_t)DFF * DM;
    const unsigned short* ap[4];
    #pragma unroll
    for (int j = 0; j < 4; ++j) ap[j] = xb + (size_t)tok[j * 32 + cr] * DM + cl;
    const unsigned short* gp[2];
    const unsigned short* up[2];
    #pragma unroll
    for (int j = 0; j < 2; ++j) {
        gp[j] = wgb + woff + (size_t)(ft * 64 + j * 32 + cr) * DM + cl;
        up[j] = wub + woff + (size_t)(ft * 64 + j * 32 + cr) * DM + cl;
    }
    unsigned short* lA = As + wave * 512;
    unsigned short* lG = Gs + wave * 512;
    unsigned short* lU = Us + wave * 512;

    f32x4 accG[2][4], accU[2][4];
    #pragma unroll
    for (int i = 0; i < 2; ++i)
        #pragma unroll
        for (int n = 0; n < 4; ++n) { accG[i][n] = (f32x4){0,0,0,0}; accU[i][n] = (f32x4){0,0,0,0}; }

    for (int k0 = 0; k0 < DM; k0 += 64) {
        __syncthreads();
        #pragma unroll
        for (int j = 0; j < 4; ++j) ASYNC16(ap[j] + k0, lA + j * 2048);
        #pragma unroll
        for (int j = 0; j < 2; ++j) {
            ASYNC16(gp[j] + k0, lG + j * 2048);
            ASYNC16(up[j] + k0, lU + j * 2048);
        }
        __syncthreads();
        #pragma unroll
        for (int ksoff = 0; ksoff < 8; ksoff += 4) {
            bf16x8 a[2], g[4], u[4];
            #pragma unroll
            for (int i = 0; i < 2; ++i) {
                int m = wave * 32 + i * 16 + col;
                a[i] = *(const bf16x8*)&As[m * 64 + ((quad + ksoff) ^ (m & 7)) * 8];
            }
            #pragma unroll
            for (int n = 0; n < 4; ++n) {
                int nb = n * 16 + col;
                int off = nb * 64 + ((quad + ksoff) ^ (nb & 7)) * 8;
                g[n] = *(const bf16x8*)&Gs[off];
                u[n] = *(const bf16x8*)&Us[off];
            }
            #pragma unroll
            for (int i = 0; i < 2; ++i)
                #pragma unroll
                for (int n = 0; n < 4; ++n) {
                    accG[i][n] = __builtin_amdgcn_mfma_f32_16x16x32_bf16(a[i], g[n], accG[i][n], 0, 0, 0);
                    accU[i][n] = __builtin_amdgcn_mfma_f32_16x16x32_bf16(a[i], u[n], accU[i][n], 0, 0, 0);
                }
        }
    }
    #pragma unroll
    for (int i = 0; i < 2; ++i) {
        #pragma unroll
        for (int r = 0; r < 4; ++r) {
            int pos = mt * 128 + wave * 32 + i * 16 + quad * 4 + r;
            if (pos >= ne) continue;
            unsigned short* hr = Hbuf + (size_t)(base + pos) * DFF + ft * 64 + col;
            #pragma unroll
            for (int n = 0; n < 4; ++n) {
                float gg = accG[i][n][r], uu = accU[i][n][r];
                float h = (gg / (1.f + expf(-gg))) * uu;
                hr[n * 16] = f2bf(h);
            }
        }
    }
}

// ---------------- GEMM2: 128Mx128N, BK=64; fully affine (slot-ordered) ----------
__global__ __launch_bounds__(256) void gemm2_kernel(
    const unsigned short* __restrict__ Hbuf, // [TOTS][DFF] slot-ordered
    const unsigned short* __restrict__ wdb,  // [NE][DM][DFF]
    const int* __restrict__ ecnt, const int* __restrict__ ebaseg,
    unsigned short* __restrict__ eo)         // [TOTS][DM] slot-ordered
{
    int e = blockIdx.z, mt = blockIdx.y, dt = blockIdx.x;
    int ne = ecnt[e];
    if (mt * 128 >= ne) return;
    int base = ebaseg[e];

    __shared__ unsigned short As[128 * 64];
    __shared__ unsigned short Bs[128 * 64];

    int tid = threadIdx.x;
    int wave = tid >> 6, lane = tid & 63;
    int quad = lane >> 4, col = lane & 15;
    int wr = (wave >> 1) * 64, wc = (wave & 1) * 64;
    int cr = tid >> 3;
    int cl = ((tid & 7) ^ (cr & 7)) * 8;

    const size_t woff = (size_t)e * (size_t)DM * DFF;
    const unsigned short* ap[4];
    const unsigned short* bp[4];
    #pragma unroll
    for (int j = 0; j < 4; ++j) {
        int hrow = min(base + mt * 128 + j * 32 + cr, TOTS - 1);
        ap[j] = Hbuf + (size_t)hrow * DFF + cl;
        bp[j] = wdb + woff + (size_t)(dt * 128 + j * 32 + cr) * DFF + cl;
    }
    unsigned short* lA = As + wave * 512;
    unsigned short* lB = Bs + wave * 512;

    f32x4 acc[4][4];
    #pragma unroll
    for (int i = 0; i < 4; ++i)
        #pragma unroll
        for (int n = 0; n < 4; ++n) acc[i][n] = (f32x4){0,0,0,0};

    for (int k0 = 0; k0 < DFF; k0 += 64) {
        __syncthreads();
        #pragma unroll
        for (int j = 0; j < 4; ++j) {
            ASYNC16(ap[j] + k0, lA + j * 2048);
            ASYNC16(bp[j] + k0, lB + j * 2048);
        }
        __syncthreads();
        #pragma unroll
        for (int ksoff = 0; ksoff < 8; ksoff += 4) {
            bf16x8 a[4], b[4];
            #pragma unroll
            for (int i = 0; i < 4; ++i) {
                int m = wr + i * 16 + col;
                a[i] = *(const bf16x8*)&As[m * 64 + ((quad + ksoff) ^ (m & 7)) * 8];
            }
            #pragma unroll
            for (int n = 0; n < 4; ++n) {
                int nb = wc + n * 16 + col;
                b[n] = *(const bf16x8*)&Bs[nb * 64 + ((quad + ksoff) ^ (nb & 7)) * 8];
            }
            #pragma unroll
            for (int i = 0; i < 4; ++i)
                #pragma unroll
                for (int n = 0; n < 4; ++n)
                    acc[i][n] = __builtin_amdgcn_mfma_f32_16x16x32_bf16(a[i], b[n], acc[i][n], 0, 0, 0);
        }
    }
    #pragma unroll
    for (int i = 0; i < 4; ++i) {
        #pragma unroll
        for (int r = 0; r < 4; ++r) {
            int pos = mt * 128 + wr + i * 16 + quad * 4 + r;
            if (pos >= ne) continue;
            unsigned short* er = eo + (size_t)(base + pos) * DM + dt * 128 + wc + col;
            #pragma unroll
            for (int n = 0; n < 4; ++n)
                er[n * 16] = f2bf(acc[i][n][r]);
        }
    }
}

// ---------------- combine: out[t] = w1*eo[row1] + w2*eo[row2] ----------------
__global__ __launch_bounds__(256) void combine_kernel(
    const unsigned short* __restrict__ eo, const float2* __restrict__ topw,
    const int2* __restrict__ cidx, float* __restrict__ out)
{
    int idx = blockIdx.x * 256 + threadIdx.x;
    int t = idx >> 7;
    int c = (idx & 127) << 3;
    float2 w = topw[t];
    int2 rr = cidx[t];
    const unsigned short* p0 = eo + (size_t)rr.x * DM + c;
    const unsigned short* p1 = eo + (size_t)rr.y * DM + c;
    ushort4 a0 = *(const ushort4*)p0;
    ushort4 a1 = *(const ushort4*)(p0 + 4);
    ushort4 b0 = *(const ushort4*)p1;
    ushort4 b1 = *(const ushort4*)(p1 + 4);
    float* orow = out + (size_t)t * DM + c;
    float4 o0, o1;
    o0.x = w.x * bf2f(a0.x) + w.y * bf2f(b0.x);
    o0.y = w.x * bf2f(a0.y) + w.y * bf2f(b0.y);
    o0.z = w.x * bf2f(a0.z) + w.y * bf2f(b0.z);
    o0.w = w.x * bf2f(a0.w) + w.y * bf2f(b0.w);
    o1.x = w.x * bf2f(a1.x) + w.y * bf2f(b1.x);
    o1.y = w.x * bf2f(a1.y) + w.y * bf2f(b1.y);
    o1.z = w.x * bf2f(a1.z) + w.y * bf2f(b1.z);
    o1.w = w.x * bf2f(a1.w) + w.y * bf2f(b1.w);
    *(float4*)orow = o0;
    *(float4*)(orow + 4) = o1;
}

extern "C" void kernel_launch(void* const* d_in, const int* in_sizes, int n_in,
                              void* d_out, int out_size, void* d_ws, size_t ws_size,
                              hipStream_t stream) {
    const float* x      = (const float*)d_in[0];
    const float* gate_w = (const float*)d_in[1];
    const float* w_gate = (const float*)d_in[2];
    const float* w_up   = (const float*)d_in[3];
    const float* w_down = (const float*)d_in[4];
    float* out = (float*)d_out;

    char* p = (char*)d_ws;
    unsigned short* xb   = (unsigned short*)p; p += (size_t)T_TOK * DM * 2;
    unsigned short* wgb  = (unsigned short*)p; p += (size_t)NE * DFF * DM * 2;
    unsigned short* wub  = (unsigned short*)p; p += (size_t)NE * DFF * DM * 2;
    unsigned short* wdb  = (unsigned short*)p; p += (size_t)NE * DM * DFF * 2;
    unsigned short* Hbuf = (unsigned short*)p; p += (size_t)TOTS * DFF * 2;
    int*   elist = (int*)p;   p += (size_t)TOTS * 4;
    int*   ecnt  = (int*)p;   p += NE * 4;
    int*   ebaseg= (int*)p;   p += NE * 4;
    int*   topi  = (int*)p;   p += (size_t)T_TOK * 4;
    float2* topw = (float2*)p; p += (size_t)T_TOK * 8;
    int2*  cidx  = (int2*)p;  p += (size_t)T_TOK * 8;
    float* psum_part = (float*)p; p += (size_t)R1_BLK * NE * 4;
    // eo aliases wgb+wub (dead after gemm1): [TOTS][DM] bf16 = 33.5 MB
    unsigned short* eo = wgb;

    pre_kernel<<<R1_BLK + CVT_BLK, 256, 0, stream>>>(
        x, gate_w, w_gate, w_up, w_down, wgb, wub, wdb,
        xb, topi, topw, psum_part);
    scatfin_kernel<<<1, 1024, 0, stream>>>(topi, psum_part, elist, cidx, ecnt, ebaseg,
                                           out + (size_t)T_TOK * DM);
    gemm1_kernel<<<dim3(DFF / 64, TOTS / 128, NE), 256, 0, stream>>>(
        xb, wgb, wub, elist, ecnt, ebaseg, Hbuf);
    gemm2_kernel<<<dim3(DM / 128, TOTS / 128, NE), 256, 0, stream>>>(
        Hbuf, wdb, ecnt, ebaseg, eo);
    combine_kernel<<<T_TOK * DM / 8 / 256, 256, 0, stream>>>(eo, topw, cidx, out);
}